// Round 14
// baseline (768.635 us; speedup 1.0000x reference)
//
#include <hip/hip_runtime.h>
#include <math.h>

#define B_ 32
#define TX_ 512
#define TY_ 2048
#define D_ 80
#define NEG (-1e9f)
#define SEG 16         // dp segment rows per buffer
#define NBUF 4         // LDS ring buffers (128 KB total)
#define NSTG 4         // stager waves

typedef float f32x4 __attribute__((ext_vector_type(4)));

#define GLB(p) ((const __attribute__((address_space(1))) void*)(p))
#define LDSP(p) ((__attribute__((address_space(3))) void*)(p))

// ---------------------------------------------------------------------------
// prep: Cc = sum_d(-0.5*log(2pi) - x_logs - 0.5*x_m^2*exp(-2*x_logs)).
// Sets *flag=1 if any x_logs != 0 (selects general vs fast gemm path).
// ---------------------------------------------------------------------------
__global__ __launch_bounds__(128) void prep_kernel(
    const float* __restrict__ x_m, const float* __restrict__ x_logs,
    float* __restrict__ Cc, int* __restrict__ flag)
{
    int row = blockIdx.x;            // b*TX + x
    int t = threadIdx.x;
    __shared__ float red[128];
    float contrib = 0.f;
    bool nz = false;
    if (t < D_) {
        float xl = x_logs[(size_t)row * D_ + t];
        float xm = x_m[(size_t)row * D_ + t];
        nz = (xl != 0.f);
        float a1 = expf(-2.f * xl);
        contrib = -0.91893853320467274178f - xl - 0.5f * xm * xm * a1;
    }
    unsigned long long m = __ballot(nz);
    if ((t & 63) == 0 && m) atomicOr(flag, 1);
    red[t] = contrib;
    __syncthreads();
    if (t < 64) {
        float v = red[t] + red[t + 64];
        #pragma unroll
        for (int off = 32; off >= 1; off >>= 1) v += __shfl_down(v, off);
        if (t == 0) Cc[row] = v;
    }
}

// ---------------------------------------------------------------------------
// lengths
// ---------------------------------------------------------------------------
__global__ __launch_bounds__(256) void lens_kernel(const float* __restrict__ x_mask,
    const float* __restrict__ z_mask, int* __restrict__ lens)
{
    int blk = blockIdx.x; int t = threadIdx.x;
    __shared__ float red[256];
    float s = 0.f;
    if (blk < B_) {
        for (int i = t; i < TX_; i += 256) s += x_mask[(size_t)blk * TX_ + i];
    } else {
        int b = blk - B_;
        for (int i = t; i < TY_; i += 256) s += z_mask[(size_t)b * TY_ + i];
    }
    red[t] = s; __syncthreads();
    for (int off = 128; off >= 1; off >>= 1) {
        if (t < off) red[t] += red[t + off];
        __syncthreads();
    }
    if (t == 0) lens[blk] = (int)(red[0] + 0.5f);
}

// ---------------------------------------------------------------------------
// gemm_zero (fast path, all x_logs==0): logpT = Cc[x] + Szz[y] + sum_d x_m*z.
// Szz computed in-block, bitwise-identical logp to the R2-passing kernel.
// ---------------------------------------------------------------------------
__global__ __launch_bounds__(256) void gemm_zero(
    const int* __restrict__ flag,
    const float* __restrict__ x_m, const float* __restrict__ Cc,
    const float* __restrict__ z,
    const float* __restrict__ x_mask, const float* __restrict__ z_mask,
    float* __restrict__ logpT, int y0, int C)
{
    if (*flag != 0) return;
    __shared__ float xs[40][132];
    __shared__ float zs[40][132];
    int b = blockIdx.z;
    int x0 = blockIdx.x * 128;
    int cy0 = blockIdx.y * 128;
    int yy0 = y0 + cy0;
    int tid = threadIdx.x;
    int tm = tid & 15, tn = tid >> 4;
    float acc[8][8];
    float accz[8];
    #pragma unroll
    for (int i = 0; i < 8; ++i) {
        accz[i] = 0.f;
        #pragma unroll
        for (int j = 0; j < 8; ++j) acc[i][j] = 0.f;
    }

    for (int h = 0; h < 2; ++h) {
        if (h) __syncthreads();
        for (int i = tid; i < 128 * 40; i += 256) {
            int m = i / 40, d = i - m * 40;
            xs[d][m] = x_m[((size_t)(b * TX_ + x0 + m)) * D_ + h * 40 + d];
        }
        for (int i = tid; i < 40 * 128; i += 256) {
            int d = i >> 7, n = i & 127;
            zs[d][n] = z[((size_t)(b * D_ + h * 40 + d)) * TY_ + yy0 + n];
        }
        __syncthreads();
        #pragma unroll 4
        for (int k = 0; k < 40; ++k) {
            f32x4 a0 = *(const f32x4*)&xs[k][tm * 4];
            f32x4 a1 = *(const f32x4*)&xs[k][64 + tm * 4];
            f32x4 z0 = *(const f32x4*)&zs[k][tn * 4];
            f32x4 z1 = *(const f32x4*)&zs[k][64 + tn * 4];
            float av[8], zv[8];
            #pragma unroll
            for (int i = 0; i < 4; ++i) { av[i] = a0[i]; av[i+4] = a1[i]; zv[i] = z0[i]; zv[i+4] = z1[i]; }
            #pragma unroll
            for (int j = 0; j < 8; ++j) {
                accz[j] = fmaf(zv[j], zv[j], accz[j]);
                #pragma unroll
                for (int i = 0; i < 8; ++i)
                    acc[i][j] = fmaf(av[i], zv[j], acc[i][j]);
            }
        }
    }
    f32x4 ccA = *(const f32x4*)&Cc[(size_t)b * TX_ + x0 + tm * 4];
    f32x4 ccB = *(const f32x4*)&Cc[(size_t)b * TX_ + x0 + 64 + tm * 4];
    f32x4 xmA = *(const f32x4*)&x_mask[(size_t)b * TX_ + x0 + tm * 4];
    f32x4 xmB = *(const f32x4*)&x_mask[(size_t)b * TX_ + x0 + 64 + tm * 4];
    #pragma unroll
    for (int jj = 0; jj < 8; ++jj) {
        int n = (jj < 4) ? (tn * 4 + jj) : (64 + tn * 4 + (jj - 4));
        float zmv = z_mask[(size_t)b * TY_ + yy0 + n];
        float sz = -0.5f * accz[jj];
        f32x4 oA, oB;
        #pragma unroll
        for (int i = 0; i < 4; ++i) {
            float vA = acc[i][jj] + ccA[i] + sz;
            float vB = acc[i + 4][jj] + ccB[i] + sz;
            oA[i] = (xmA[i] * zmv > 0.f) ? vA : NEG;
            oB[i] = (xmB[i] * zmv > 0.f) ? vB : NEG;
        }
        float* orow = &logpT[((size_t)b * C + cy0 + n) * TX_ + x0];
        *(f32x4*)(orow + tm * 4) = oA;
        *(f32x4*)(orow + 64 + tm * 4) = oB;
    }
}

// ---------------------------------------------------------------------------
// gemm_logp (general path): logpT = Cc + sum_d a1*(-0.5 z^2) + a2*z, masked.
// ---------------------------------------------------------------------------
__global__ __launch_bounds__(256) void gemm_logp(
    const int* __restrict__ flag,
    const float* __restrict__ x_m, const float* __restrict__ x_logs,
    const float* __restrict__ Cc,
    const float* __restrict__ z, const float* __restrict__ x_mask, const float* __restrict__ z_mask,
    float* __restrict__ logpT, int y0, int C)
{
    if (*flag == 0) return;
    __shared__ float A1s[D_][72];
    __shared__ float A2s[D_][72];
    __shared__ float zs[D_][64];
    int b = blockIdx.z;
    int x0 = blockIdx.x * 64;
    int cy0 = blockIdx.y * 64;
    int yy0 = y0 + cy0;
    int tid = threadIdx.x;
    for (int i = tid; i < 64 * D_; i += 256) {
        int m = i / D_, d = i - m * D_;
        size_t ga = ((size_t)(b * TX_ + x0 + m)) * D_ + d;
        float xl = x_logs[ga], xm = x_m[ga];
        float a1 = expf(-2.f * xl);
        A1s[d][m] = a1;
        A2s[d][m] = xm * a1;
    }
    for (int i = tid; i < D_ * 64; i += 256) {
        int d = i >> 6, n = i & 63;
        zs[d][n] = z[((size_t)(b * D_ + d)) * TY_ + yy0 + n];
    }
    __syncthreads();
    int tm = tid & 15, tn = tid >> 4;
    float acc[4][4];
    #pragma unroll
    for (int i = 0; i < 4; ++i)
        #pragma unroll
        for (int j = 0; j < 4; ++j) acc[i][j] = 0.f;
    #pragma unroll 4
    for (int k = 0; k < D_; ++k) {
        f32x4 a1 = *(const f32x4*)&A1s[k][tm * 4];
        f32x4 a2 = *(const f32x4*)&A2s[k][tm * 4];
        f32x4 zv = *(const f32x4*)&zs[k][tn * 4];
        #pragma unroll
        for (int j = 0; j < 4; ++j) {
            float h = -0.5f * zv[j];
            #pragma unroll
            for (int i = 0; i < 4; ++i) {
                float tt = fmaf(h, a1[i], a2[i]);
                acc[i][j] = fmaf(zv[j], tt, acc[i][j]);
            }
        }
    }
    f32x4 cc = *(const f32x4*)&Cc[(size_t)b * TX_ + x0 + tm * 4];
    f32x4 xm = *(const f32x4*)&x_mask[(size_t)b * TX_ + x0 + tm * 4];
    #pragma unroll
    for (int j = 0; j < 4; ++j) {
        int n = tn * 4 + j;
        float zmv = z_mask[(size_t)b * TY_ + yy0 + n];
        f32x4 o;
        #pragma unroll
        for (int i = 0; i < 4; ++i) {
            float val = acc[i][j] + cc[i];
            o[i] = (xm[i] * zmv > 0.f) ? val : NEG;
        }
        *(f32x4*)&logpT[((size_t)b * C + cy0 + n) * TX_ + x0 + tm * 4] = o;
    }
}

// ---------------------------------------------------------------------------
// Viterbi forward — deep-pipelined producer/consumer staging.
// R13 post-mortem: dp is per-CU FETCH-CONCURRENCY bound (848 cyc/step =
// 2KB/step at 2.4 B/cyc/CU; the swizzle null-result killed the bank-conflict
// theory — the 524288 counter is a fixed per-b128 artifact). R11's
// vmcnt(0)-per-segment drained the pipe to zero every segment (~30% duty).
// Here: 1 consumer wave + 4 stager waves, 4x16-row LDS ring (128 KB),
// stagers run 3 segments ahead with per-wave COUNTED vmcnt (each wave owns
// exactly 8 of the 32 DMA units per segment -> uniform ledger):
//   issue seg g+3 (8 DMAs), s_waitcnt vmcnt(16)  -> oldest 8 (seg g+1) in
//   LDS, 16-24 DMAs (24-36 KB) per wave stay in flight ACROSS barriers.
// Tail steps the count down 16 -> 8 -> 0 (wave-uniform branches).
// Consumer loop identical to the twice-passed R11 form (mapping A, one
// shfl_up, byte stores).
// ---------------------------------------------------------------------------
__device__ __forceinline__ unsigned int dp_step(int y, int lane, const f32x4 la, const f32x4 lb,
    float (&f)[8], unsigned int laneMask)
{
    float lp8[8];
    #pragma unroll
    for (int i = 0; i < 4; ++i) { lp8[i] = la[i]; lp8[i + 4] = lb[i]; }
    float sh = __shfl_up(f[7], 1);
    float edge = (y == 0) ? 0.f : NEG;
    float pm0 = (lane == 0) ? edge : sh;
    bool lanehit = (lane == (y >> 3));     // false for y >= 512 -> plain step
    int jeq = y & 7;
    unsigned int byt = 0u;
    #pragma unroll
    for (int j = 7; j >= 0; --j) {         // descending: f[j-1] still old
        float pm = (j == 0) ? pm0 : f[j - 1];
        bool ceq = lanehit && (jeq == j);
        byt = byt * 2u + (((f[j] < pm) || ceq) ? 1u : 0u);
        float vc = ceq ? NEG : f[j];
        f[j] = lp8[j] + fmaxf(pm, vc);
    }
    return byt & laneMask;
}

__device__ __forceinline__ void stage_seg(const char* gbase, float (*dst)[TX_],
    int sw, int t0)
{
    // 32 DMA units per segment: unit d covers row s=d>>1, half h=d&1
    // (1KB = 64 lanes x 16B each). Wave sw takes d = sw, sw+4, ... (8 units).
    #pragma unroll
    for (int d0 = 0; d0 < 2 * SEG; d0 += NSTG) {
        int d = d0 + sw;
        int s = d >> 1, h = d & 1;
        const char* g = gbase + ((size_t)(t0 + s) * TX_ + h * 256) * 4;
        __builtin_amdgcn_global_load_lds(GLB(g), LDSP(&dst[s][h * 256]), 16, 0, 0);
    }
}

__global__ __launch_bounds__(320, 1) void dp_forward(const float* __restrict__ logpT,
    float* __restrict__ fsave, unsigned char* __restrict__ bits8, int y0, int C)
{
    __shared__ float buf[NBUF][SEG][TX_];  // 128 KB ring
    int b = blockIdx.x, tid = threadIdx.x;
    int w = tid >> 6, lane = tid & 63;
    const char* gbase = (const char*)(logpT + (size_t)b * C * TX_) + lane * 16;
    unsigned char* bp = bits8 + ((size_t)b * TY_ + y0) * 64 + lane;
    int nseg = C / SEG;                    // >= 8 always

    float f[8];
    unsigned int laneMask = (lane == 0) ? 0xFEu : 0xFFu;
    if (w == 0) {
        if (y0 == 0) {
            #pragma unroll
            for (int j = 0; j < 8; ++j) f[j] = NEG;
        } else {
            f32x4 fa = *(const f32x4*)(fsave + (size_t)b * TX_ + lane * 8);
            f32x4 fb = *(const f32x4*)(fsave + (size_t)b * TX_ + lane * 8 + 4);
            #pragma unroll
            for (int j = 0; j < 4; ++j) { f[j] = fa[j]; f[j + 4] = fb[j]; }
        }
    } else {
        #pragma unroll
        for (int j = 0; j < 8; ++j) f[j] = 0.f;   // unused
    }

    if (w >= 1) {
        int sw = w - 1;
        stage_seg(gbase, buf[0], sw, 0);
        stage_seg(gbase, buf[1], sw, SEG);
        stage_seg(gbase, buf[2], sw, 2 * SEG);
        asm volatile("s_waitcnt vmcnt(16)" ::: "memory");   // seg 0 resident
    }
    __syncthreads();

    for (int g = 0; g < nseg; ++g) {
        if (w == 0) {
            float (*cur)[TX_] = buf[g & (NBUF - 1)];
            int t0 = g * SEG;
            #pragma unroll 8
            for (int s = 0; s < SEG; ++s) {
                f32x4 la = *(const f32x4*)&cur[s][lane * 8];
                f32x4 lb = *(const f32x4*)&cur[s][lane * 8 + 4];
                unsigned int byt = dp_step(y0 + t0 + s, lane, la, lb, f, laneMask);
                bp[(size_t)(t0 + s) * 64] = (unsigned char)byt;
            }
        } else {
            int sw = w - 1;
            if (g + 3 < nseg)
                stage_seg(gbase, buf[(g + 3) & (NBUF - 1)], sw, (g + 3) * SEG);
            // per-wave ledger: outstanding = 8 * (#segs g+1..min(g+3,nseg-1));
            // need oldest 8 (seg g+1) retired before the barrier.
            if (g + 3 < nseg)       asm volatile("s_waitcnt vmcnt(16)" ::: "memory");
            else if (g + 3 == nseg) asm volatile("s_waitcnt vmcnt(8)"  ::: "memory");
            else if (g + 2 == nseg) asm volatile("s_waitcnt vmcnt(0)"  ::: "memory");
            // g+1 == nseg: last iter, nothing left to guarantee
        }
        __syncthreads();
    }

    if (w == 0) {
        f32x4 fa, fb;
        #pragma unroll
        for (int j = 0; j < 4; ++j) { fa[j] = f[j]; fb[j] = f[j + 4]; }
        *(f32x4*)(fsave + (size_t)b * TX_ + lane * 8) = fa;
        *(f32x4*)(fsave + (size_t)b * TX_ + lane * 8 + 4) = fb;
    }
}

// ---------------------------------------------------------------------------
// Backtrack. One wave per batch. (bits8 layout unchanged.)
// ---------------------------------------------------------------------------
__global__ __launch_bounds__(64) void backtrack_kernel(
    const unsigned char* __restrict__ bits8, const int* __restrict__ lens,
    const float* __restrict__ x_mask, int* __restrict__ idxA, float* __restrict__ logdur)
{
    int b = blockIdx.x, lane = threadIdx.x;
    __shared__ int durS[TX_];
    for (int x = lane; x < TX_; x += 64) durS[x] = 0;
    int tx_len = lens[b];
    int ty_len = lens[B_ + b];
    int idx = tx_len - 1;
    if (idx < 0) idx = 0;
    int cnt = 0;
    const unsigned long long* bu = (const unsigned long long*)(bits8 + (size_t)b * TY_ * 64);
    for (int w = 0; w < TY_ / 64; ++w) {
        int ytop = TY_ - 1 - w * 64;
        int yl = ytop - lane;
        int Whi = idx >> 6;
        unsigned long long whi = bu[(size_t)yl * 8 + Whi];
        unsigned long long wlo = (Whi > 0) ? bu[(size_t)yl * 8 + Whi - 1] : 0ull;
        int rec = -1;
        for (int s = 0; s < 64; ++s) {
            int y = ytop - s;
            bool active = (y < ty_len);
            if (lane == s) rec = active ? idx : -1;
            if (active) cnt++;
            unsigned long long wsel = ((idx >> 6) == Whi) ? __shfl(whi, s) : __shfl(wlo, s);
            int bit = (int)((wsel >> (idx & 63)) & 1ull);
            if (active && bit) {
                if (lane == 0) durS[idx] = cnt;
                cnt = 0;
                idx -= 1;
            }
        }
        idxA[(size_t)b * TY_ + yl] = rec;
    }
    if (lane == 0) durS[idx] = cnt;
    __syncthreads();
    for (int x = lane; x < TX_; x += 64) {
        float dv = (float)durS[x];
        logdur[(size_t)b * TX_ + x] = logf(1e-8f + dv) * x_mask[(size_t)b * TX_ + x];
    }
}

// ---------------------------------------------------------------------------
__global__ __launch_bounds__(256) void attn_write(const int* __restrict__ idxA,
    const float* __restrict__ x_mask, const float* __restrict__ z_mask,
    float* __restrict__ attn_o)
{
    int b = blockIdx.z; int x = blockIdx.y;
    int yq = blockIdx.x * 256 + threadIdx.x;
    int4 iv = ((const int4*)(idxA + (size_t)b * TY_))[yq];
    float xm = x_mask[(size_t)b * TX_ + x];
    float4 zm4 = ((const float4*)(z_mask + (size_t)b * TY_))[yq];
    float4 o;
    o.x = (iv.x == x) ? xm * zm4.x : 0.f;
    o.y = (iv.y == x) ? xm * zm4.y : 0.f;
    o.z = (iv.z == x) ? xm * zm4.z : 0.f;
    o.w = (iv.w == x) ? xm * zm4.w : 0.f;
    ((float4*)(attn_o + ((size_t)(b * TX_ + x)) * TY_))[yq] = o;
}

__global__ __launch_bounds__(256) void zm_write(const int* __restrict__ idxA,
    const float* __restrict__ x_m, const float* __restrict__ x_logs,
    const float* __restrict__ x_mask, const float* __restrict__ z_mask,
    float* __restrict__ z_m_o, float* __restrict__ z_logs_o)
{
    int b = blockIdx.z; int d = blockIdx.y;
    int yq = blockIdx.x * 256 + threadIdx.x;
    int4 iv = ((const int4*)(idxA + (size_t)b * TY_))[yq];
    float4 zm4 = ((const float4*)(z_mask + (size_t)b * TY_))[yq];
    float4 om, ol;
    float* omv = (float*)&om; float* olv = (float*)&ol;
    int ivv[4] = {iv.x, iv.y, iv.z, iv.w};
    float zmv[4] = {zm4.x, zm4.y, zm4.z, zm4.w};
    #pragma unroll
    for (int c = 0; c < 4; ++c) {
        float vm = 0.f, vl = 0.f;
        int ix = ivv[c];
        if (ix >= 0) {
            float wgt = x_mask[(size_t)b * TX_ + ix] * zmv[c];
            size_t ga = ((size_t)(b * TX_ + ix)) * D_ + d;
            vm = wgt * x_m[ga];
            vl = wgt * x_logs[ga];
        }
        omv[c] = vm; olv[c] = vl;
    }
    ((float4*)(z_m_o    + ((size_t)(b * D_ + d)) * TY_))[yq] = om;
    ((float4*)(z_logs_o + ((size_t)(b * D_ + d)) * TY_))[yq] = ol;
}

// ---------------------------------------------------------------------------
extern "C" void kernel_launch(void* const* d_in, const int* in_sizes, int n_in,
                              void* d_out, int out_size, void* d_ws, size_t ws_size,
                              hipStream_t stream)
{
    const float* x_m    = (const float*)d_in[0];   // [B,TX,D]
    const float* x_logs = (const float*)d_in[1];   // [B,TX,D]
    const float* z      = (const float*)d_in[2];   // [B,D,TY]
    const float* x_mask = (const float*)d_in[3];   // [B,1,TX]
    const float* z_mask = (const float*)d_in[4];   // [B,1,TY]
    float* out = (float*)d_out;
    float* z_m_o    = out;                                   // [B,D,TY]
    float* z_logs_o = out + (size_t)B_ * D_ * TY_;           // [B,D,TY]
    float* logdur_o = out + (size_t)2 * B_ * D_ * TY_;       // [B,1,TX]
    float* attn_o   = logdur_o + (size_t)B_ * TX_;           // [B,TX,TY]

    char* p = (char*)d_ws;
    float* Cc = (float*)p;            p += (size_t)B_ * TX_ * 4;
    float* fs = (float*)p;            p += (size_t)B_ * TX_ * 4;
    unsigned char* bits8 = (unsigned char*)p; p += (size_t)B_ * TY_ * 64;
    int* idxA = (int*)p;              p += (size_t)B_ * TY_ * 4;
    int* lens = (int*)p;              p += 256;
    int* flag = (int*)p;              p += 256;
    float* logpC = (float*)p;
    size_t fixed = (size_t)(p - (char*)d_ws);
    size_t avail = (ws_size > fixed) ? (ws_size - fixed) : 0;
    int C = 128;                                   // Ty chunk for staged logp
    const int cands[5] = {2048, 1024, 512, 256, 128};
    for (int i = 0; i < 5; ++i) {
        if ((size_t)B_ * cands[i] * TX_ * 4 <= avail) { C = cands[i]; break; }
    }

    hipMemsetAsync(flag, 0, sizeof(int), stream);
    prep_kernel<<<B_ * TX_, 128, 0, stream>>>(x_m, x_logs, Cc, flag);
    lens_kernel<<<2 * B_, 256, 0, stream>>>(x_mask, z_mask, lens);
    int nc = TY_ / C;
    for (int c = 0; c < nc; ++c) {
        gemm_zero<<<dim3(TX_ / 128, C / 128, B_), 256, 0, stream>>>(
            flag, x_m, Cc, z, x_mask, z_mask, logpC, c * C, C);
        gemm_logp<<<dim3(TX_ / 64, C / 64, B_), 256, 0, stream>>>(
            flag, x_m, x_logs, Cc, z, x_mask, z_mask, logpC, c * C, C);
        dp_forward<<<B_, 320, 0, stream>>>(logpC, fs, bits8, c * C, C);
    }
    backtrack_kernel<<<B_, 64, 0, stream>>>(bits8, lens, x_mask, idxA, logdur_o);
    attn_write<<<dim3(TY_ / 4 / 256, TX_, B_), 256, 0, stream>>>(idxA, x_mask, z_mask, attn_o);
    zm_write<<<dim3(TY_ / 4 / 256, D_, B_), 256, 0, stream>>>(
        idxA, x_m, x_logs, x_mask, z_mask, z_m_o, z_logs_o);
}

// Round 15
// 690.931 us; speedup vs baseline: 1.1125x; 1.1125x over previous
//
#include <hip/hip_runtime.h>
#include <math.h>

#define B_ 32
#define TX_ 512
#define TY_ 2048
#define D_ 80
#define NEG (-1e9f)
#define PF 16

typedef float f32x4 __attribute__((ext_vector_type(4)));

// ---------------------------------------------------------------------------
// prep: Cc = sum_d(-0.5*log(2pi) - x_logs - 0.5*x_m^2*exp(-2*x_logs)).
// Sets *flag=1 if any x_logs != 0 (selects general vs fast gemm path).
// ---------------------------------------------------------------------------
__global__ __launch_bounds__(128) void prep_kernel(
    const float* __restrict__ x_m, const float* __restrict__ x_logs,
    float* __restrict__ Cc, int* __restrict__ flag)
{
    int row = blockIdx.x;            // b*TX + x
    int t = threadIdx.x;
    __shared__ float red[128];
    float contrib = 0.f;
    bool nz = false;
    if (t < D_) {
        float xl = x_logs[(size_t)row * D_ + t];
        float xm = x_m[(size_t)row * D_ + t];
        nz = (xl != 0.f);
        float a1 = expf(-2.f * xl);
        contrib = -0.91893853320467274178f - xl - 0.5f * xm * xm * a1;
    }
    unsigned long long m = __ballot(nz);
    if ((t & 63) == 0 && m) atomicOr(flag, 1);
    red[t] = contrib;
    __syncthreads();
    if (t < 64) {
        float v = red[t] + red[t + 64];
        #pragma unroll
        for (int off = 32; off >= 1; off >>= 1) v += __shfl_down(v, off);
        if (t == 0) Cc[row] = v;
    }
}

// ---------------------------------------------------------------------------
// lengths
// ---------------------------------------------------------------------------
__global__ __launch_bounds__(256) void lens_kernel(const float* __restrict__ x_mask,
    const float* __restrict__ z_mask, int* __restrict__ lens)
{
    int blk = blockIdx.x; int t = threadIdx.x;
    __shared__ float red[256];
    float s = 0.f;
    if (blk < B_) {
        for (int i = t; i < TX_; i += 256) s += x_mask[(size_t)blk * TX_ + i];
    } else {
        int b = blk - B_;
        for (int i = t; i < TY_; i += 256) s += z_mask[(size_t)b * TY_ + i];
    }
    red[t] = s; __syncthreads();
    for (int off = 128; off >= 1; off >>= 1) {
        if (t < off) red[t] += red[t + off];
        __syncthreads();
    }
    if (t == 0) lens[blk] = (int)(red[0] + 0.5f);
}

// ---------------------------------------------------------------------------
// gemm_zero (fast path, all x_logs==0): logpT = Cc[x] + Szz[y] + sum_d x_m*z.
// Szz computed in-block, bitwise-identical logp to the R2-passing kernel.
// ---------------------------------------------------------------------------
__global__ __launch_bounds__(256) void gemm_zero(
    const int* __restrict__ flag,
    const float* __restrict__ x_m, const float* __restrict__ Cc,
    const float* __restrict__ z,
    const float* __restrict__ x_mask, const float* __restrict__ z_mask,
    float* __restrict__ logpT, int y0, int C)
{
    if (*flag != 0) return;
    __shared__ float xs[40][132];
    __shared__ float zs[40][132];
    int b = blockIdx.z;
    int x0 = blockIdx.x * 128;
    int cy0 = blockIdx.y * 128;
    int yy0 = y0 + cy0;
    int tid = threadIdx.x;
    int tm = tid & 15, tn = tid >> 4;
    float acc[8][8];
    float accz[8];
    #pragma unroll
    for (int i = 0; i < 8; ++i) {
        accz[i] = 0.f;
        #pragma unroll
        for (int j = 0; j < 8; ++j) acc[i][j] = 0.f;
    }

    for (int h = 0; h < 2; ++h) {
        if (h) __syncthreads();
        for (int i = tid; i < 128 * 40; i += 256) {
            int m = i / 40, d = i - m * 40;
            xs[d][m] = x_m[((size_t)(b * TX_ + x0 + m)) * D_ + h * 40 + d];
        }
        for (int i = tid; i < 40 * 128; i += 256) {
            int d = i >> 7, n = i & 127;
            zs[d][n] = z[((size_t)(b * D_ + h * 40 + d)) * TY_ + yy0 + n];
        }
        __syncthreads();
        #pragma unroll 4
        for (int k = 0; k < 40; ++k) {
            f32x4 a0 = *(const f32x4*)&xs[k][tm * 4];
            f32x4 a1 = *(const f32x4*)&xs[k][64 + tm * 4];
            f32x4 z0 = *(const f32x4*)&zs[k][tn * 4];
            f32x4 z1 = *(const f32x4*)&zs[k][64 + tn * 4];
            float av[8], zv[8];
            #pragma unroll
            for (int i = 0; i < 4; ++i) { av[i] = a0[i]; av[i+4] = a1[i]; zv[i] = z0[i]; zv[i+4] = z1[i]; }
            #pragma unroll
            for (int j = 0; j < 8; ++j) {
                accz[j] = fmaf(zv[j], zv[j], accz[j]);
                #pragma unroll
                for (int i = 0; i < 8; ++i)
                    acc[i][j] = fmaf(av[i], zv[j], acc[i][j]);
            }
        }
    }
    f32x4 ccA = *(const f32x4*)&Cc[(size_t)b * TX_ + x0 + tm * 4];
    f32x4 ccB = *(const f32x4*)&Cc[(size_t)b * TX_ + x0 + 64 + tm * 4];
    f32x4 xmA = *(const f32x4*)&x_mask[(size_t)b * TX_ + x0 + tm * 4];
    f32x4 xmB = *(const f32x4*)&x_mask[(size_t)b * TX_ + x0 + 64 + tm * 4];
    #pragma unroll
    for (int jj = 0; jj < 8; ++jj) {
        int n = (jj < 4) ? (tn * 4 + jj) : (64 + tn * 4 + (jj - 4));
        float zmv = z_mask[(size_t)b * TY_ + yy0 + n];
        float sz = -0.5f * accz[jj];
        f32x4 oA, oB;
        #pragma unroll
        for (int i = 0; i < 4; ++i) {
            float vA = acc[i][jj] + ccA[i] + sz;
            float vB = acc[i + 4][jj] + ccB[i] + sz;
            oA[i] = (xmA[i] * zmv > 0.f) ? vA : NEG;
            oB[i] = (xmB[i] * zmv > 0.f) ? vB : NEG;
        }
        float* orow = &logpT[((size_t)b * C + cy0 + n) * TX_ + x0];
        *(f32x4*)(orow + tm * 4) = oA;
        *(f32x4*)(orow + 64 + tm * 4) = oB;
    }
}

// ---------------------------------------------------------------------------
// gemm_logp (general path): logpT = Cc + sum_d a1*(-0.5 z^2) + a2*z, masked.
// ---------------------------------------------------------------------------
__global__ __launch_bounds__(256) void gemm_logp(
    const int* __restrict__ flag,
    const float* __restrict__ x_m, const float* __restrict__ x_logs,
    const float* __restrict__ Cc,
    const float* __restrict__ z, const float* __restrict__ x_mask, const float* __restrict__ z_mask,
    float* __restrict__ logpT, int y0, int C)
{
    if (*flag == 0) return;
    __shared__ float A1s[D_][72];
    __shared__ float A2s[D_][72];
    __shared__ float zs[D_][64];
    int b = blockIdx.z;
    int x0 = blockIdx.x * 64;
    int cy0 = blockIdx.y * 64;
    int yy0 = y0 + cy0;
    int tid = threadIdx.x;
    for (int i = tid; i < 64 * D_; i += 256) {
        int m = i / D_, d = i - m * D_;
        size_t ga = ((size_t)(b * TX_ + x0 + m)) * D_ + d;
        float xl = x_logs[ga], xm = x_m[ga];
        float a1 = expf(-2.f * xl);
        A1s[d][m] = a1;
        A2s[d][m] = xm * a1;
    }
    for (int i = tid; i < D_ * 64; i += 256) {
        int d = i >> 6, n = i & 63;
        zs[d][n] = z[((size_t)(b * D_ + d)) * TY_ + yy0 + n];
    }
    __syncthreads();
    int tm = tid & 15, tn = tid >> 4;
    float acc[4][4];
    #pragma unroll
    for (int i = 0; i < 4; ++i)
        #pragma unroll
        for (int j = 0; j < 4; ++j) acc[i][j] = 0.f;
    #pragma unroll 4
    for (int k = 0; k < D_; ++k) {
        f32x4 a1 = *(const f32x4*)&A1s[k][tm * 4];
        f32x4 a2 = *(const f32x4*)&A2s[k][tm * 4];
        f32x4 zv = *(const f32x4*)&zs[k][tn * 4];
        #pragma unroll
        for (int j = 0; j < 4; ++j) {
            float h = -0.5f * zv[j];
            #pragma unroll
            for (int i = 0; i < 4; ++i) {
                float tt = fmaf(h, a1[i], a2[i]);
                acc[i][j] = fmaf(zv[j], tt, acc[i][j]);
            }
        }
    }
    f32x4 cc = *(const f32x4*)&Cc[(size_t)b * TX_ + x0 + tm * 4];
    f32x4 xm = *(const f32x4*)&x_mask[(size_t)b * TX_ + x0 + tm * 4];
    #pragma unroll
    for (int j = 0; j < 4; ++j) {
        int n = tn * 4 + j;
        float zmv = z_mask[(size_t)b * TY_ + yy0 + n];
        f32x4 o;
        #pragma unroll
        for (int i = 0; i < 4; ++i) {
            float val = acc[i][j] + cc[i];
            o[i] = (xm[i] * zmv > 0.f) ? val : NEG;
        }
        *(f32x4*)&logpT[((size_t)b * C + cy0 + n) * TX_ + x0 + tm * 4] = o;
    }
}

// ---------------------------------------------------------------------------
// Viterbi forward — R7 consumer + cache-warming prefetcher wave.
// R14 post-mortem: every structure that couples the consumer to LDS/waitcnt
// lands at ~860 cyc/step; the plain-global consumer lands at ~580 cyc/step
// = one LLC-read latency (its prefetch ring collapses to depth ~1-2, five
// attempts). So: leave the consumer EXACTLY as the twice-passed R7 loop and
// add wave 1 as a prefetcher that streams the block's 2MB logp slice into
// the local XCD's L2 ahead of consumption (1 dword/lane @64B stride = 2
// rows/load, unroll 8 -> 8 loads in flight; results kept live via += and an
// asm sink, rule #17). Pacing: volatile LDS progress counter, prefetcher
// stays <=256 rows ahead (512KB/block, 4 blocks/XCD = 2MB < 4MB L2).
// Consumer never waits on prefetcher (no deadlock); its collapsed ring then
// pays ~200cyc L2-hit latency instead of ~600cyc LLC.
// ---------------------------------------------------------------------------
__device__ __forceinline__ void dp_stepN(int lane, const float4 la, const float4 lb,
    float (&f)[8], unsigned int laneMask, unsigned char* bpp)
{
    float lp8[8] = {la.x, la.y, la.z, la.w, lb.x, lb.y, lb.z, lb.w};
    float sh = __shfl_up(f[7], 1);
    float pm0 = (lane == 0) ? NEG : sh;
    unsigned int byt = 0u;
    #pragma unroll
    for (int j = 7; j >= 0; --j) {            // descending: f[j-1] still old
        float pm = (j == 0) ? pm0 : f[j - 1];
        byt = byt * 2u + ((f[j] < pm) ? 1u : 0u);
        f[j] = lp8[j] + fmaxf(pm, f[j]);
    }
    *bpp = (unsigned char)(byt & laneMask);
}

__device__ __forceinline__ void dp_stepD(int y, int lane, const float4 la, const float4 lb,
    float (&f)[8], unsigned int laneMask, unsigned char* bpp)
{
    float lp8[8] = {la.x, la.y, la.z, la.w, lb.x, lb.y, lb.z, lb.w};
    float sh = __shfl_up(f[7], 1);
    float edge = (y == 0) ? 0.f : NEG;
    float pm0 = (lane == 0) ? edge : sh;
    bool lanehit = (lane == (y >> 3));
    int jeq = y & 7;
    unsigned int byt = 0u;
    #pragma unroll
    for (int j = 7; j >= 0; --j) {
        float pm = (j == 0) ? pm0 : f[j - 1];
        bool ceq = lanehit && (jeq == j);
        byt = byt * 2u + (((f[j] < pm) || ceq) ? 1u : 0u);
        float vc = ceq ? NEG : f[j];
        f[j] = lp8[j] + fmaxf(pm, vc);
    }
    *bpp = (unsigned char)(byt & laneMask);
}

__global__ __launch_bounds__(128, 1) void dp_forward(const float* __restrict__ logpT,
    float* __restrict__ fsave, unsigned char* __restrict__ bits8, int y0, int C)
{
    __shared__ int progS;
    int b = blockIdx.x, tid = threadIdx.x;
    int w = tid >> 6, lane = tid & 63;
    volatile int* prog = &progS;
    if (tid == 0) progS = 0;
    __syncthreads();

    const float* base = logpT + (size_t)b * C * TX_;

    if (w == 1) {
        // ---- prefetcher wave: warm L2, <=256 rows ahead of consumer ----
        const char* pb = (const char*)base + lane * 64;
        float acc = 0.f;
        for (int t = 0; t < C; t += 16) {          // 16 rows per outer iter
            while (t - *prog > 256) __builtin_amdgcn_s_sleep(8);
            #pragma unroll
            for (int u = 0; u < 8; ++u) {          // 8 loads in flight
                acc += *(const float*)(pb + (size_t)(t + 2 * u) * 2048);
            }
        }
        asm volatile("" :: "v"(acc));              // keep loads live (no DCE)
        return;
    }

    // ---- consumer wave: byte-identical R7 loop ----
    const float* lp = base + lane * 8;
    unsigned char* bp = bits8 + ((size_t)b * TY_ + y0) * 64 + lane;
    float f[8];
    if (y0 == 0) {
        #pragma unroll
        for (int j = 0; j < 8; ++j) f[j] = NEG;
    } else {
        float4 fa = *(const float4*)(fsave + (size_t)b * TX_ + lane * 8);
        float4 fb = *(const float4*)(fsave + (size_t)b * TX_ + lane * 8 + 4);
        f[0]=fa.x; f[1]=fa.y; f[2]=fa.z; f[3]=fa.w;
        f[4]=fb.x; f[5]=fb.y; f[6]=fb.z; f[7]=fb.w;
    }
    unsigned int laneMask = (lane == 0) ? 0xFEu : 0xFFu;

    float4 bufA[PF], bufB[PF];
    #pragma unroll
    for (int s = 0; s < PF; ++s) {            // C >= 128 > PF always
        bufA[s] = *(const float4*)(lp + (size_t)s * TX_);
        bufB[s] = *(const float4*)(lp + (size_t)s * TX_ + 4);
    }
    int tD = 0;
    if (y0 < TX_) { tD = TX_ - y0; if (tD > C) tD = C; }   // multiple of PF
    int t = 0;
    for (; t < tD; t += PF) {
        if (lane == 0) *prog = t;
        #pragma unroll
        for (int s = 0; s < PF; ++s) {
            dp_stepD(y0 + t + s, lane, bufA[s], bufB[s], f, laneMask, bp + (size_t)(t + s) * 64);
            int tn = t + s + PF; if (tn >= C) tn = C - 1;
            bufA[s] = *(const float4*)(lp + (size_t)tn * TX_);
            bufB[s] = *(const float4*)(lp + (size_t)tn * TX_ + 4);
        }
    }
    for (; t < C; t += PF) {
        if (lane == 0) *prog = t;
        #pragma unroll
        for (int s = 0; s < PF; ++s) {
            dp_stepN(lane, bufA[s], bufB[s], f, laneMask, bp + (size_t)(t + s) * 64);
            int tn = t + s + PF; if (tn >= C) tn = C - 1;
            bufA[s] = *(const float4*)(lp + (size_t)tn * TX_);
            bufB[s] = *(const float4*)(lp + (size_t)tn * TX_ + 4);
        }
    }
    if (lane == 0) *prog = C;
    float4 fa = make_float4(f[0], f[1], f[2], f[3]);
    float4 fb = make_float4(f[4], f[5], f[6], f[7]);
    *(float4*)(fsave + (size_t)b * TX_ + lane * 8) = fa;
    *(float4*)(fsave + (size_t)b * TX_ + lane * 8 + 4) = fb;
}

// ---------------------------------------------------------------------------
// Backtrack. One wave per batch.
// ---------------------------------------------------------------------------
__global__ __launch_bounds__(64) void backtrack_kernel(
    const unsigned char* __restrict__ bits8, const int* __restrict__ lens,
    const float* __restrict__ x_mask, int* __restrict__ idxA, float* __restrict__ logdur)
{
    int b = blockIdx.x, lane = threadIdx.x;
    __shared__ int durS[TX_];
    for (int x = lane; x < TX_; x += 64) durS[x] = 0;
    int tx_len = lens[b];
    int ty_len = lens[B_ + b];
    int idx = tx_len - 1;
    if (idx < 0) idx = 0;
    int cnt = 0;
    const unsigned long long* bu = (const unsigned long long*)(bits8 + (size_t)b * TY_ * 64);
    for (int w = 0; w < TY_ / 64; ++w) {
        int ytop = TY_ - 1 - w * 64;
        int yl = ytop - lane;
        int Whi = idx >> 6;
        unsigned long long whi = bu[(size_t)yl * 8 + Whi];
        unsigned long long wlo = (Whi > 0) ? bu[(size_t)yl * 8 + Whi - 1] : 0ull;
        int rec = -1;
        for (int s = 0; s < 64; ++s) {
            int y = ytop - s;
            bool active = (y < ty_len);
            if (lane == s) rec = active ? idx : -1;
            if (active) cnt++;
            unsigned long long wsel = ((idx >> 6) == Whi) ? __shfl(whi, s) : __shfl(wlo, s);
            int bit = (int)((wsel >> (idx & 63)) & 1ull);
            if (active && bit) {
                if (lane == 0) durS[idx] = cnt;
                cnt = 0;
                idx -= 1;
            }
        }
        idxA[(size_t)b * TY_ + yl] = rec;
    }
    if (lane == 0) durS[idx] = cnt;
    __syncthreads();
    for (int x = lane; x < TX_; x += 64) {
        float dv = (float)durS[x];
        logdur[(size_t)b * TX_ + x] = logf(1e-8f + dv) * x_mask[(size_t)b * TX_ + x];
    }
}

// ---------------------------------------------------------------------------
__global__ __launch_bounds__(256) void attn_write(const int* __restrict__ idxA,
    const float* __restrict__ x_mask, const float* __restrict__ z_mask,
    float* __restrict__ attn_o)
{
    int b = blockIdx.z; int x = blockIdx.y;
    int yq = blockIdx.x * 256 + threadIdx.x;
    int4 iv = ((const int4*)(idxA + (size_t)b * TY_))[yq];
    float xm = x_mask[(size_t)b * TX_ + x];
    float4 zm4 = ((const float4*)(z_mask + (size_t)b * TY_))[yq];
    float4 o;
    o.x = (iv.x == x) ? xm * zm4.x : 0.f;
    o.y = (iv.y == x) ? xm * zm4.y : 0.f;
    o.z = (iv.z == x) ? xm * zm4.z : 0.f;
    o.w = (iv.w == x) ? xm * zm4.w : 0.f;
    ((float4*)(attn_o + ((size_t)(b * TX_ + x)) * TY_))[yq] = o;
}

__global__ __launch_bounds__(256) void zm_write(const int* __restrict__ idxA,
    const float* __restrict__ x_m, const float* __restrict__ x_logs,
    const float* __restrict__ x_mask, const float* __restrict__ z_mask,
    float* __restrict__ z_m_o, float* __restrict__ z_logs_o)
{
    int b = blockIdx.z; int d = blockIdx.y;
    int yq = blockIdx.x * 256 + threadIdx.x;
    int4 iv = ((const int4*)(idxA + (size_t)b * TY_))[yq];
    float4 zm4 = ((const float4*)(z_mask + (size_t)b * TY_))[yq];
    float4 om, ol;
    float* omv = (float*)&om; float* olv = (float*)&ol;
    int ivv[4] = {iv.x, iv.y, iv.z, iv.w};
    float zmv[4] = {zm4.x, zm4.y, zm4.z, zm4.w};
    #pragma unroll
    for (int c = 0; c < 4; ++c) {
        float vm = 0.f, vl = 0.f;
        int ix = ivv[c];
        if (ix >= 0) {
            float wgt = x_mask[(size_t)b * TX_ + ix] * zmv[c];
            size_t ga = ((size_t)(b * TX_ + ix)) * D_ + d;
            vm = wgt * x_m[ga];
            vl = wgt * x_logs[ga];
        }
        omv[c] = vm; olv[c] = vl;
    }
    ((float4*)(z_m_o    + ((size_t)(b * D_ + d)) * TY_))[yq] = om;
    ((float4*)(z_logs_o + ((size_t)(b * D_ + d)) * TY_))[yq] = ol;
}

// ---------------------------------------------------------------------------
extern "C" void kernel_launch(void* const* d_in, const int* in_sizes, int n_in,
                              void* d_out, int out_size, void* d_ws, size_t ws_size,
                              hipStream_t stream)
{
    const float* x_m    = (const float*)d_in[0];   // [B,TX,D]
    const float* x_logs = (const float*)d_in[1];   // [B,TX,D]
    const float* z      = (const float*)d_in[2];   // [B,D,TY]
    const float* x_mask = (const float*)d_in[3];   // [B,1,TX]
    const float* z_mask = (const float*)d_in[4];   // [B,1,TY]
    float* out = (float*)d_out;
    float* z_m_o    = out;                                   // [B,D,TY]
    float* z_logs_o = out + (size_t)B_ * D_ * TY_;           // [B,D,TY]
    float* logdur_o = out + (size_t)2 * B_ * D_ * TY_;       // [B,1,TX]
    float* attn_o   = logdur_o + (size_t)B_ * TX_;           // [B,TX,TY]

    char* p = (char*)d_ws;
    float* Cc = (float*)p;            p += (size_t)B_ * TX_ * 4;
    float* fs = (float*)p;            p += (size_t)B_ * TX_ * 4;
    unsigned char* bits8 = (unsigned char*)p; p += (size_t)B_ * TY_ * 64;
    int* idxA = (int*)p;              p += (size_t)B_ * TY_ * 4;
    int* lens = (int*)p;              p += 256;
    int* flag = (int*)p;              p += 256;
    float* logpC = (float*)p;
    size_t fixed = (size_t)(p - (char*)d_ws);
    size_t avail = (ws_size > fixed) ? (ws_size - fixed) : 0;
    int C = 128;                                   // Ty chunk for staged logp
    const int cands[5] = {2048, 1024, 512, 256, 128};
    for (int i = 0; i < 5; ++i) {
        if ((size_t)B_ * cands[i] * TX_ * 4 <= avail) { C = cands[i]; break; }
    }

    hipMemsetAsync(flag, 0, sizeof(int), stream);
    prep_kernel<<<B_ * TX_, 128, 0, stream>>>(x_m, x_logs, Cc, flag);
    lens_kernel<<<2 * B_, 256, 0, stream>>>(x_mask, z_mask, lens);
    int nc = TY_ / C;
    for (int c = 0; c < nc; ++c) {
        gemm_zero<<<dim3(TX_ / 128, C / 128, B_), 256, 0, stream>>>(
            flag, x_m, Cc, z, x_mask, z_mask, logpC, c * C, C);
        gemm_logp<<<dim3(TX_ / 64, C / 64, B_), 256, 0, stream>>>(
            flag, x_m, x_logs, Cc, z, x_mask, z_mask, logpC, c * C, C);
        dp_forward<<<B_, 128, 0, stream>>>(logpC, fs, bits8, c * C, C);
    }
    backtrack_kernel<<<B_, 64, 0, stream>>>(bits8, lens, x_mask, idxA, logdur_o);
    attn_write<<<dim3(TY_ / 4 / 256, TX_, B_), 256, 0, stream>>>(idxA, x_mask, z_mask, attn_o);
    zm_write<<<dim3(TY_ / 4 / 256, D_, B_), 256, 0, stream>>>(
        idxA, x_m, x_logs, x_mask, z_mask, z_m_o, z_logs_o);
}